// Round 12
// baseline (162.585 us; speedup 1.0000x reference)
//
#include <hip/hip_runtime.h>
#include <hip/hip_bf16.h>

#define NB 32768      // batch rows per node
#define CD 128        // input channels
#define NNODES 6
#define OUTW 1536     // 6*256 output cols
#define KW 256        // concat K per node GEMM
#define GPB 4         // row-groups per block
#define NBLK (NB / 16 / GPB)   // 512 blocks = 2 per CU

typedef __attribute__((ext_vector_type(8))) short short8;
typedef __attribute__((ext_vector_type(4))) short s16x4;   // 'short4' is a HIP builtin
typedef __attribute__((ext_vector_type(4))) float f32x4;

// hardware f32->bf16 (RNE)
static __device__ __forceinline__ short f2bf(float f) {
    union { __bf16 b; short s; } u;
    u.b = (__bf16)f;
    return u.s;
}

static __device__ __forceinline__ short8 pack8(f32x4 a, f32x4 b) {
    short8 p;
    #pragma unroll
    for (int j = 0; j < 4; ++j) { p[j] = f2bf(a[j]); p[4 + j] = f2bf(b[j]); }
    return p;
}

static __device__ __forceinline__ s16x4 pack4(f32x4 a) {
    s16x4 p;
    #pragma unroll
    for (int j = 0; j < 4; ++j) p[j] = f2bf(a[j]);
    return p;
}

// ---- prologue: Wcat[o][k] bf16 in d_ws; k<128 -> Wl[o][k], else Wr[o][k-128]
__global__ void prep_w(const float* __restrict__ Wl, const float* __restrict__ Wr,
                       short* __restrict__ Wb) {
    const int i = (blockIdx.x * 256 + threadIdx.x) * 8;
    const int o = i >> 8;
    const int k = i & 255;
    const float* src = (k < 128) ? (Wl + o * CD + k) : (Wr + o * CD + (k - 128));
    *(short8*)(Wb + i) = pack8(*(const f32x4*)src, *(const f32x4*)(src + 4));
}

// LDS short-index, XOR swizzle (byte ^= (r&7)<<4): panel p(0..9), row r(0..15),
// k(0..127). Bijective for 8B/16B accesses; reads 2-way max. Verified R5-R11.
#define LIDX(p, r, k) ((((p) << 11) + ((r) << 7) + (k)) ^ (((r) & 7) << 3))

// R12: store-overlap pipeline + node-split waves.
// Per iter: {MFMA(A[cur]) -> convert(xv -> A[nxt]) -> ONE barrier ->
// load(it+2 -> xv) -> GELU+stores(it)}. Stores drain at the NEXT iter's
// barrier after overlapping a full MFMA+convert phase; xv loads precede
// stores in program order so the compiler's xv wait is a counted vmcnt
// that skips stores. Wave = (node-group ng, 64-col strip): 6 panel-frags
// per k-chunk instead of 10 (-40% LDS instr), W-loads 2x but L2-hot.
// Panel map (R8-validated): ng0 nodes{0,1,2} aggs{g0,g1,g25}=panels{0,1,2},
// x panels {4,5,6}; ng1 nodes{3,4,5} aggs{g34,g34,g25}={3,3,2}, x {7,8,9}.
__global__ __launch_bounds__(512, 2)
void sage_v10(const float* __restrict__ x, const short* __restrict__ Wb,
              const float* __restrict__ bias, float* __restrict__ out) {
    __shared__ __align__(16) short A[2][10 * 16 * 128];   // 2 x 40 KB

    const int t = threadIdx.x;
    const int r = t >> 5;          // convert row 0..15
    const int c = t & 31;          // 4-float chunk 0..31
    const int lane = t & 63;
    const int wv = t >> 6;
    const int ng = wv >> 2;        // node group
    const int strip = wv & 3;      // 64-col strip
    const int lo = lane & 15;
    const int hi = lane >> 4;
    const int paA = ng ? 3 : 0;
    const int paB = ng ? 3 : 1;    // ng1: same as paA (CSE'd read)
    const int pxb = 4 + ng * 3;
    const size_t rg0 = (size_t)blockIdx.x * GPB;

    f32x4 xv[NNODES];

    auto load_xv = [&](size_t rg) {
        const float* pb = x + (rg * 16 + r) * CD + c * 4;
        #pragma unroll
        for (int s = 0; s < NNODES; ++s)
            xv[s] = *(const f32x4*)(pb + (size_t)s * (NB * CD));
    };
    auto convert = [&](short* __restrict__ Ad) {
        f32x4 S01 = xv[0] + xv[1], S25 = xv[2] + xv[5], S34 = xv[3] + xv[4];
        f32x4 T = S01 + S25 + S34;
        const int k = c * 4;
        *(s16x4*)&Ad[LIDX(0, r, k)] = pack4((T - xv[0]) * 0.2f);      // g0
        *(s16x4*)&Ad[LIDX(1, r, k)] = pack4((T - xv[1]) * 0.2f);      // g1
        *(s16x4*)&Ad[LIDX(2, r, k)] = pack4((S01 + S34) * 0.25f);     // g25
        *(s16x4*)&Ad[LIDX(3, r, k)] = pack4((S01 + S25) * 0.25f);     // g34
        #pragma unroll
        for (int s = 0; s < NNODES; ++s)
            *(s16x4*)&Ad[LIDX(4 + s, r, k)] = pack4(xv[s]);
    };

    // pipeline prologue: group 0 -> A[0]; issue group 1 loads
    load_xv(rg0);
    convert(&A[0][0]);
    if (GPB > 1) load_xv(rg0 + 1);
    __syncthreads();

    #pragma unroll 1
    for (int it = 0; it < GPB; ++it) {
        const short* Ab = &A[it & 1][0];

        f32x4 acc[3][4];
        #pragma unroll
        for (int n = 0; n < 3; ++n)
            #pragma unroll
            for (int i = 0; i < 4; ++i) acc[n][i] = (f32x4){0.f, 0.f, 0.f, 0.f};

        #pragma unroll
        for (int m = 0; m < 4; ++m) {
            const int kk = m * 32 + hi * 8;
            short8 fgA = *(const short8*)&Ab[LIDX(paA, lo, kk)];
            short8 fgB = *(const short8*)&Ab[LIDX(paB, lo, kk)];
            short8 fgC = *(const short8*)&Ab[LIDX(2,   lo, kk)];
            short8 fx0 = *(const short8*)&Ab[LIDX(pxb + 0, lo, kk)];
            short8 fx1 = *(const short8*)&Ab[LIDX(pxb + 1, lo, kk)];
            short8 fx2 = *(const short8*)&Ab[LIDX(pxb + 2, lo, kk)];
            #pragma unroll
            for (int i = 0; i < 4; ++i) {
                const int o = strip * 64 + i * 16 + lo;
                short8 wa = *(const short8*)&Wb[o * KW + kk];          // Wl half
                short8 wx = *(const short8*)&Wb[o * KW + 128 + kk];    // Wr half
                acc[0][i] = __builtin_amdgcn_mfma_f32_16x16x32_bf16(wa, fgA, acc[0][i], 0, 0, 0);
                acc[1][i] = __builtin_amdgcn_mfma_f32_16x16x32_bf16(wa, fgB, acc[1][i], 0, 0, 0);
                acc[2][i] = __builtin_amdgcn_mfma_f32_16x16x32_bf16(wa, fgC, acc[2][i], 0, 0, 0);
                acc[0][i] = __builtin_amdgcn_mfma_f32_16x16x32_bf16(wx, fx0, acc[0][i], 0, 0, 0);
                acc[1][i] = __builtin_amdgcn_mfma_f32_16x16x32_bf16(wx, fx1, acc[1][i], 0, 0, 0);
                acc[2][i] = __builtin_amdgcn_mfma_f32_16x16x32_bf16(wx, fx2, acc[2][i], 0, 0, 0);
            }
        }

        // convert next group (consumes xv loaded last iter; disjoint buffer
        // from all concurrent MFMA reads -> single barrier suffices)
        if (it + 1 < GPB) convert(&A[(it + 1) & 1][0]);
        __syncthreads();

        // issue loads for it+2 BEFORE stores: xv wait stays a counted vmcnt
        if (it + 2 < GPB) load_xv(rg0 + it + 2);

        // epilogue stores for group it: drain at NEXT iter's barrier after
        // overlapping its full MFMA+convert phase
        const size_t orow = (rg0 + it) * 16 + lo;
        #pragma unroll
        for (int n = 0; n < 3; ++n) {
            #pragma unroll
            for (int i = 0; i < 4; ++i) {
                const int ocol = strip * 64 + i * 16 + hi * 4;   // within-node channel
                const int col = (ng * 3 + n) * 256 + ocol;
                f32x4 v = acc[n][i] + *(const f32x4*)&bias[ocol];
                f32x4 g;
                #pragma unroll
                for (int j = 0; j < 4; ++j) {
                    const float s = v[j] * (0.7978845608f + 0.0356774081f * v[j] * v[j]);
                    const float rr = __builtin_amdgcn_exp2f(-2.885390082f * s);
                    g[j] = v[j] * __builtin_amdgcn_rcpf(1.0f + rr);
                }
                *(f32x4*)&out[orow * OUTW + col] = g;
            }
        }
    }
}

extern "C" void kernel_launch(void* const* d_in, const int* in_sizes, int n_in,
                              void* d_out, int out_size, void* d_ws, size_t ws_size,
                              hipStream_t stream) {
    const float* x  = (const float*)d_in[0];
    const float* Wl = (const float*)d_in[1];
    const float* Wr = (const float*)d_in[2];
    const float* b  = (const float*)d_in[3];
    float* out = (float*)d_out;
    short* Wb = (short*)d_ws;   // 256*256 bf16 = 128 KB

    prep_w<<<dim3(32), dim3(256), 0, stream>>>(Wl, Wr, Wb);
    sage_v10<<<dim3(NBLK), dim3(512), 0, stream>>>(x, Wb, b, out);
}

// Round 13
// 83.825 us; speedup vs baseline: 1.9396x; 1.9396x over previous
//
#include <hip/hip_runtime.h>
#include <hip/hip_bf16.h>

#define NB 32768      // batch rows per node
#define CD 128        // input channels
#define NNODES 6
#define OUTW 1536     // 6*256 output cols
#define KW 256        // concat K per node GEMM
#define GPB 8         // row-groups per persistent block
#define NBLK (NB / 16 / GPB)   // 256 blocks = 1 per CU

typedef __attribute__((ext_vector_type(8))) short short8;
typedef __attribute__((ext_vector_type(4))) short s16x4;   // 'short4' is a HIP builtin
typedef __attribute__((ext_vector_type(4))) float f32x4;

// hardware f32->bf16 (RNE)
static __device__ __forceinline__ short f2bf(float f) {
    union { __bf16 b; short s; } u;
    u.b = (__bf16)f;
    return u.s;
}

static __device__ __forceinline__ short8 pack8(f32x4 a, f32x4 b) {
    short8 p;
    #pragma unroll
    for (int j = 0; j < 4; ++j) { p[j] = f2bf(a[j]); p[4 + j] = f2bf(b[j]); }
    return p;
}

static __device__ __forceinline__ s16x4 pack4(f32x4 a) {
    s16x4 p;
    #pragma unroll
    for (int j = 0; j < 4; ++j) p[j] = f2bf(a[j]);
    return p;
}

// ---- prologue: Wcat[o][k] bf16 in d_ws; k<128 -> Wl[o][k], else Wr[o][k-128]
__global__ void prep_w(const float* __restrict__ Wl, const float* __restrict__ Wr,
                       short* __restrict__ Wb) {
    const int i = (blockIdx.x * 256 + threadIdx.x) * 8;
    const int o = i >> 8;
    const int k = i & 255;
    const float* src = (k < 128) ? (Wl + o * CD + k) : (Wr + o * CD + (k - 128));
    *(short8*)(Wb + i) = pack8(*(const f32x4*)src, *(const f32x4*)(src + 4));
}

// LDS short-index, XOR swizzle (byte ^= (r&7)<<4): panel p(0..9), row r(0..15),
// k(0..127). Bijective for 8B/16B accesses; reads 2-way max. Verified R5-R12.
// Panels: 0:g0 1:g1 2:g25 3:g34 4..9:x0..x5
#define LIDX(p, r, k) ((((p) << 11) + ((r) << 7) + (k)) ^ (((r) & 7) << 3))

// R13 = R11's DMA pipeline (proven best, 92us) with store-drain fix:
// MFMA phase split into 3 node-PAIRS sharing agg panels -- (0,1),(2,5),(3,4)
// -- each pair's stores issue right after its accumulation, so at every
// s_waitcnt vmcnt(0) (inside __syncthreads) the stores have had 1/3-2/3 of
// the MFMA phase to drain instead of 0 (R11 exposed ~3.6us/iter of drain).
// acc shrinks to [2][2]=16 regs: no spill possible (R9/R12 failure mode).
__global__ __launch_bounds__(512, 2)
void sage_v11(const float* __restrict__ x, const short* __restrict__ Wb,
              const float* __restrict__ bias, float* __restrict__ out) {
    __shared__ __align__(16) float raw[2][NNODES * 16 * 128];   // 2 x 48 KB, linear
    __shared__ __align__(16) short A[10 * 16 * 128];            // 40 KB panels

    const int t = threadIdx.x;
    const int r = t >> 5;          // staging/convert row 0..15
    const int c = t & 31;          // 4-float chunk 0..31
    const int lane = t & 63;
    const int wv = t >> 6;         // wave 0..7
    const int lo = lane & 15;
    const int hi = lane >> 4;
    const int obase = wv * 32;     // 32-col strip per wave (R10/R11-validated)
    const size_t rg0 = (size_t)blockIdx.x * GPB;

    // bias is per-node-channel (256), hoisted: one f32x4 per i-tile
    f32x4 bias4[2];
    #pragma unroll
    for (int i = 0; i < 2; ++i)
        bias4[i] = *(const f32x4*)&bias[obase + i * 16 + hi * 4];

    // ---- async DMA of one row-group's raw x into raw[buf] (R11-verbatim:
    // wave-uniform LDS base + lane*16B matches the global per-lane addresses)
    auto stage = [&](int buf, size_t rg) {
        const float* gp = x + (rg * 16 + r) * CD + c * 4;
        #pragma unroll
        for (int s = 0; s < NNODES; ++s) {
            __builtin_amdgcn_global_load_lds(
                (const __attribute__((address_space(1))) void*)(gp + (size_t)s * (NB * CD)),
                (__attribute__((address_space(3))) void*)&raw[buf][s * 2048 + wv * 256],
                16, 0, 0);
        }
    };

    // ---- convert raw[buf] -> bf16 panels (R11-verbatim)
    auto convert = [&](int buf) {
        const float* rb = &raw[buf][0];
        const int base = r * 128 + c * 4;
        f32x4 v0 = *(const f32x4*)&rb[0 * 2048 + base];
        f32x4 v1 = *(const f32x4*)&rb[1 * 2048 + base];
        f32x4 v2 = *(const f32x4*)&rb[2 * 2048 + base];
        f32x4 v3 = *(const f32x4*)&rb[3 * 2048 + base];
        f32x4 v4 = *(const f32x4*)&rb[4 * 2048 + base];
        f32x4 v5 = *(const f32x4*)&rb[5 * 2048 + base];
        f32x4 S01 = v0 + v1, S25 = v2 + v5, S34 = v3 + v4;
        f32x4 T = S01 + S25 + S34;
        const int k = c * 4;
        *(s16x4*)&A[LIDX(0, r, k)] = pack4((T - v0) * 0.2f);      // g0
        *(s16x4*)&A[LIDX(1, r, k)] = pack4((T - v1) * 0.2f);      // g1
        *(s16x4*)&A[LIDX(2, r, k)] = pack4((S01 + S34) * 0.25f);  // g25
        *(s16x4*)&A[LIDX(3, r, k)] = pack4((S01 + S25) * 0.25f);  // g34
        *(s16x4*)&A[LIDX(4, r, k)] = pack4(v0);
        *(s16x4*)&A[LIDX(5, r, k)] = pack4(v1);
        *(s16x4*)&A[LIDX(6, r, k)] = pack4(v2);
        *(s16x4*)&A[LIDX(7, r, k)] = pack4(v3);
        *(s16x4*)&A[LIDX(8, r, k)] = pack4(v4);
        *(s16x4*)&A[LIDX(9, r, k)] = pack4(v5);
    };

    // ---- one node-pair's MFMA accumulation (agg panels pa0/pa1 may be equal
    // -> compiler CSEs the duplicate LDS read; x panels px0/px1)
    auto pairMFMA = [&](int pa0, int pa1, int px0, int px1, f32x4 acc[2][2]) {
        #pragma unroll
        for (int n = 0; n < 2; ++n)
            #pragma unroll
            for (int i = 0; i < 2; ++i) acc[n][i] = (f32x4){0.f, 0.f, 0.f, 0.f};
        #pragma unroll
        for (int m = 0; m < 4; ++m) {
            const int kk = m * 32 + hi * 8;
            short8 fa0 = *(const short8*)&A[LIDX(pa0, lo, kk)];
            short8 fa1 = *(const short8*)&A[LIDX(pa1, lo, kk)];
            short8 fx0 = *(const short8*)&A[LIDX(px0, lo, kk)];
            short8 fx1 = *(const short8*)&A[LIDX(px1, lo, kk)];
            #pragma unroll
            for (int i = 0; i < 2; ++i) {
                const int o = obase + i * 16 + lo;
                short8 wa = *(const short8*)&Wb[o * KW + kk];          // Wl half
                short8 wx = *(const short8*)&Wb[o * KW + 128 + kk];    // Wr half
                acc[0][i] = __builtin_amdgcn_mfma_f32_16x16x32_bf16(wa, fa0, acc[0][i], 0, 0, 0);
                acc[1][i] = __builtin_amdgcn_mfma_f32_16x16x32_bf16(wa, fa1, acc[1][i], 0, 0, 0);
                acc[0][i] = __builtin_amdgcn_mfma_f32_16x16x32_bf16(wx, fx0, acc[0][i], 0, 0, 0);
                acc[1][i] = __builtin_amdgcn_mfma_f32_16x16x32_bf16(wx, fx1, acc[1][i], 0, 0, 0);
            }
        }
    };

    // ---- GELU + stores for one node pair (lane f32x4 = 4 consecutive cols)
    auto storePair = [&](int n0, int n1, f32x4 acc[2][2], size_t orow) {
        #pragma unroll
        for (int w = 0; w < 2; ++w) {
            const int node = w ? n1 : n0;
            #pragma unroll
            for (int i = 0; i < 2; ++i) {
                const int ocol = obase + i * 16 + hi * 4;
                f32x4 v = acc[w][i] + bias4[i];
                f32x4 g;
                #pragma unroll
                for (int j = 0; j < 4; ++j) {
                    const float s = v[j] * (0.7978845608f + 0.0356774081f * v[j] * v[j]);
                    const float rr = __builtin_amdgcn_exp2f(-2.885390082f * s);
                    g[j] = v[j] * __builtin_amdgcn_rcpf(1.0f + rr);
                }
                *(f32x4*)&out[orow * OUTW + node * 256 + ocol] = g;
            }
        }
    };

    // ---- pipeline prologue: group 0
    stage(0, rg0);
    __syncthreads();               // drains vmcnt -> DMA complete
    convert(0);
    __syncthreads();

    #pragma unroll 1
    for (int it = 0; it < GPB; ++it) {
        const bool havenext = (it + 1 < GPB);
        if (havenext) stage((it + 1) & 1, rg0 + it + 1);   // overlaps MFMA phase

        const size_t orow = (rg0 + it) * 16 + lo;
        f32x4 acc[2][2];

        pairMFMA(0, 1, 4, 5, acc);            // nodes 0,1 (g0,g1)
        storePair(0, 1, acc, orow);           // stores drain under pairs 1,2
        pairMFMA(2, 2, 6, 9, acc);            // nodes 2,5 (shared g25)
        storePair(2, 5, acc, orow);           // drain under pair 2 + convert
        pairMFMA(3, 3, 7, 8, acc);            // nodes 3,4 (shared g34)

        __syncthreads();                      // MFMA reads of A done; DMA drained
        storePair(3, 4, acc, orow);           // drains under convert
        if (havenext) convert((it + 1) & 1);  // raw[nxt] -> panels
        __syncthreads();
    }
}

extern "C" void kernel_launch(void* const* d_in, const int* in_sizes, int n_in,
                              void* d_out, int out_size, void* d_ws, size_t ws_size,
                              hipStream_t stream) {
    const float* x  = (const float*)d_in[0];
    const float* Wl = (const float*)d_in[1];
    const float* Wr = (const float*)d_in[2];
    const float* b  = (const float*)d_in[3];
    float* out = (float*)d_out;
    short* Wb = (short*)d_ws;   // 256*256 bf16 = 128 KB

    prep_w<<<dim3(32), dim3(256), 0, stream>>>(Wl, Wr, Wb);
    sage_v11<<<dim3(NBLK), dim3(512), 0, stream>>>(x, Wb, b, out);
}